// Round 13
// baseline (226.932 us; speedup 1.0000x reference)
//
#include <hip/hip_runtime.h>
#include <math.h>

#define B_ 2
#define S_ 2048
#define E_ 1024
#define H_ 16
#define HD_ 64
#define LAMBDA_INIT 0.8f
#define EPS_ 1e-6f

typedef __attribute__((ext_vector_type(8))) short short8;   // 8 bf16 (4 VGPRs)
typedef __attribute__((ext_vector_type(8))) unsigned short ushort8v;
typedef __attribute__((ext_vector_type(4))) float floatx4;  // MFMA C/D 16x16
typedef __attribute__((ext_vector_type(16))) float floatx16; // MFMA C/D 32x32

__device__ __forceinline__ unsigned short f2bf(float f) {
  unsigned u = __float_as_uint(f);
  u += 0x7FFFu + ((u >> 16) & 1u);   // RNE
  return (unsigned short)(u >> 16);
}

__device__ __forceinline__ void gl_lds16(const void* g, void* l) {
  __builtin_amdgcn_global_load_lds((const __attribute__((address_space(1))) void*)g,
                                   (__attribute__((address_space(3))) void*)l,
                                   16, 0, 0);
}

// ---------------------------------------------------------------------------
// prep: fused {cast x -> bf16} + {transpose_cast w_qkv} + {transpose_cast wo}.
// [Byte-identical to verified R10.]
// ---------------------------------------------------------------------------
__global__ __launch_bounds__(256) void prep(const float* __restrict__ x,
                                            const float* __restrict__ w_qkv,
                                            const float* __restrict__ wo,
                                            unsigned short* __restrict__ xB,
                                            unsigned short* __restrict__ WT,
                                            unsigned short* __restrict__ woT) {
  __shared__ float tile[64][65];
  const int tid = threadIdx.x;
  const int bid = blockIdx.x;
  if (bid < 1024) {
    const int n4 = 4096 * 1024 / 4;
    for (int i = bid * 256 + tid; i < n4; i += 1024 * 256) {
      float4 v = ((const float4*)x)[i];
      ushort4 w;
      w.x = f2bf(v.x); w.y = f2bf(v.y); w.z = f2bf(v.z); w.w = f2bf(v.w);
      ((ushort4*)xB)[i] = w;
    }
    return;
  }
  const float* in;
  unsigned short* out;
  int R, C, bx, by;
  if (bid < 1792) {
    in = w_qkv; out = WT; R = 1024; C = 3072;
    int t = bid - 1024; bx = t % 48; by = t / 48;
  } else {
    in = wo; out = woT; R = 1024; C = 1024;
    int t = bid - 1792; bx = t % 16; by = t / 16;
  }
  const int c0 = bx * 64;
  const int r0 = by * 64;
#pragma unroll
  for (int it = 0; it < 16; it++) {
    int e = tid + it * 256;
    int rr = e >> 6, cc = e & 63;
    tile[rr][cc] = in[(size_t)(r0 + rr) * C + c0 + cc];
  }
  __syncthreads();
#pragma unroll
  for (int it = 0; it < 16; it++) {
    int e = tid + it * 256;
    int rr = e >> 6, cc = e & 63;
    out[(size_t)(c0 + rr) * R + r0 + cc] = f2bf(tile[cc][rr]);
  }
}

// ---------------------------------------------------------------------------
// bf16 MFMA GEMM body: C[M][N] = A[M][K] @ B[K][N], B given TRANSPOSED as
// Bt[N][K]. Tile 128 x BNT, 256 thr (4 waves). CHANGED (R13): BK 64 -> 32
// with double-buffer -> LDS halves to 32KB (qkv: 2 -> 4 blocks/CU) while
// keeping the verified 1-barrier dbuf pipeline. K still ascends in the same
// MFMA order per accumulator -> bitwise-identical C. Swizzle re-derived for
// 32-col rows: phys = quad ^ ((r>>1)&3) (same bank-class balance as the
// verified BK=64 ^(r&7) scheme).
// ---------------------------------------------------------------------------
template <bool BF16OUT, int BNT>
__device__ __forceinline__ void gemm_body(unsigned short* AsB, unsigned short* BsB,
                                          const unsigned short* __restrict__ A,
                                          const unsigned short* __restrict__ Bt,
                                          void* __restrict__ C, int M, int N, int K,
                                          int bx, int by) {
  const int tid = threadIdx.x;
  const int wave = tid >> 6, lane = tid & 63;
  const int lane15 = lane & 15, quad = lane >> 4;
  const int m0 = by * 128;
  const int n0 = bx * BNT;
  const int wm = (wave & 1) * 64, wn = (wave >> 1) * (BNT / 2);
  const int NI = BNT / 32;   // n-fragments per wave
  const int RB = BNT / 64;   // B staging rounds (1 or 2)

  floatx4 acc[4][NI];
#pragma unroll
  for (int mi = 0; mi < 4; mi++)
#pragma unroll
    for (int ni = 0; ni < NI; ni++) acc[mi][ni] = (floatx4)0.0f;

  const int lrow = lane >> 2;   // row within a 16-row staging round
  const int cph = lane & 3;     // physical 16B chunk slot this lane fills

  // stage one 32-col K-tile: A 128x32 (2 rounds), B BNTx32 (RB rounds)
#define GSTAGE(k0_, As_, Bs_)                                                  \
  {                                                                            \
    _Pragma("unroll")                                                          \
    for (int j = 0; j < 2; j++) {                                              \
      int r = wave * 32 + lrow + j * 16;                                       \
      int cl = cph ^ ((r >> 1) & 3);                                           \
      gl_lds16(A + (size_t)(m0 + r) * K + (k0_) + cl * 8,                      \
               (As_) + (wave * 32 + j * 16) * 32);                             \
    }                                                                          \
    _Pragma("unroll")                                                          \
    for (int j = 0; j < RB; j++) {                                             \
      int r = wave * (BNT / 4) + lrow + j * 16;                                \
      int cl = cph ^ ((r >> 1) & 3);                                           \
      gl_lds16(Bt + (size_t)(n0 + r) * K + (k0_) + cl * 8,                     \
               (Bs_) + (wave * (BNT / 4) + j * 16) * 32);                      \
    }                                                                          \
  }

  // prologue: stage k-tile 0 into buffer 0 (__syncthreads drains vmcnt(0))
  GSTAGE(0, AsB, BsB);
  __syncthreads();

  int cur = 0;
  for (int k0 = 0; k0 < K; k0 += 32) {
    if (k0 + 32 < K)
      GSTAGE(k0 + 32, AsB + (cur ^ 1) * (128 * 32), BsB + (cur ^ 1) * (BNT * 32));
    const unsigned short* As = AsB + cur * (128 * 32);
    const unsigned short* Bs = BsB + cur * (BNT * 32);

    short8 af[4], bf[NI];
#pragma unroll
    for (int mi = 0; mi < 4; mi++) {
      int r = wm + mi * 16 + lane15;
      int phys = quad ^ ((r >> 1) & 3);
      af[mi] = *(const short8*)(&As[r * 32 + phys * 8]);
    }
#pragma unroll
    for (int ni = 0; ni < NI; ni++) {
      int r = wn + ni * 16 + lane15;
      int phys = quad ^ ((r >> 1) & 3);
      bf[ni] = *(const short8*)(&Bs[r * 32 + phys * 8]);
    }
#pragma unroll
    for (int mi = 0; mi < 4; mi++)
#pragma unroll
      for (int ni = 0; ni < NI; ni++)
        acc[mi][ni] = __builtin_amdgcn_mfma_f32_16x16x32_bf16(af[mi], bf[ni],
                                                              acc[mi][ni], 0, 0, 0);
    __syncthreads();   // drains vmcnt(0): next tile staged; cur reads done
    cur ^= 1;
  }
#undef GSTAGE

#pragma unroll
  for (int mi = 0; mi < 4; mi++)
#pragma unroll
    for (int ni = 0; ni < NI; ni++)
#pragma unroll
      for (int reg = 0; reg < 4; reg++) {
        int row = m0 + wm + mi * 16 + quad * 4 + reg;
        int col = n0 + wn + ni * 16 + lane15;
        float v = acc[mi][ni][reg];
        if (BF16OUT)
          ((unsigned short*)C)[(size_t)row * N + col] = f2bf(v);
        else
          ((float*)C)[(size_t)row * N + col] = v;
      }
}

template <bool BF16OUT, int BNT>
__global__ __launch_bounds__(256, BNT == 64 ? 2 : 1) void gemm_bt(
    const unsigned short* __restrict__ A, const unsigned short* __restrict__ Bt,
    void* __restrict__ C, int M, int N, int K) {
  __shared__ __align__(16) unsigned short As[2 * 128 * 32];
  __shared__ __align__(16) unsigned short Bs[2 * BNT * 32];
  gemm_body<BF16OUT, BNT>(As, Bs, A, Bt, C, M, N, K, blockIdx.x, blockIdx.y);
}

// 32KB LDS + VGPR cap 128 -> 4 blocks/CU co-resident (entire 1024-block grid)
__global__ __launch_bounds__(256, 4) void qkv_gemm(
    const unsigned short* __restrict__ xB, const unsigned short* __restrict__ WT,
    unsigned short* __restrict__ qkB, unsigned short* __restrict__ vTB) {
  __shared__ __align__(16) unsigned short As[2 * 128 * 32];
  __shared__ __align__(16) unsigned short Bs[2 * 128 * 32];
  const int id = blockIdx.x;
  if (id < 512) {
    gemm_body<true, 128>(As, Bs, xB, WT, qkB, 4096, 2048, 1024, id & 15, id >> 4);
  } else {
    const int t = id - 512;
    gemm_body<true, 64>(As, Bs, WT + (size_t)2048 * 1024, xB, vTB, 1024, 4096, 1024,
                        t & 63, t >> 6);
  }
}

// ---------------------------------------------------------------------------
// MFMA flash differential attention, 32x32x16 swapped-QK^T, SPLIT-S waves.
// [Math/staging/exchange byte-identical to verified R9/R10/R12.] NEW (R13):
// T5 s_setprio(1) wrapping the QK and PV MFMA clusters only -- pure runtime
// scheduler hint, no memory/ordering semantics, cannot change results.
// NOTE: split-kb (16 waves) failed correctness twice (R3, R11); axis retired.
// ---------------------------------------------------------------------------
__global__ __launch_bounds__(512, 4) void flash_attn_mfma(
    const unsigned short* __restrict__ qkB, const unsigned short* __restrict__ vTB,
    const float* __restrict__ lq1, const float* __restrict__ lq2,
    const float* __restrict__ lk1, const float* __restrict__ lk2,
    const float* __restrict__ norm_w, unsigned short* __restrict__ hid) {
  __shared__ __align__(16) unsigned short KV[2][2][64 * 64];   // [buf][0=K,1=V]
  __shared__ float Lex[4][64];                                 // sw=1 lsum
  __shared__ float LF2[64][130];                               // [d][q] out tile

  const int tid = threadIdx.x;
  const int wave = tid >> 6, lane = tid & 63;
  const int l31 = lane & 31, hi = lane >> 5;
  const int qsub = wave >> 1, sw = wave & 1;

  // bijective XCD swizzle: the 16 q-tiles sharing one (b,h)'s K/V land on one XCD
  const int bid = (blockIdx.x & 7) * 64 + (blockIdx.x >> 3);   // 512 blocks
  const int qt = bid & 15;
  const int h = (bid >> 4) & 15;
  const int b = bid >> 8;
  const int q0 = qt * 128;

  float a1 = 0.f, a2 = 0.f;
  for (int d = 0; d < HD_; d++) {
    a1 += lq1[d] * lk1[d];
    a2 += lq2[d] * lk2[d];
  }
  const float lam = __expf(a1) - __expf(a2) + LAMBDA_INIT;

  // Q fragments for MY branch: Q[q = q0+qsub*32+l31][h*64 + sw*32 + cs*16 + hi*8]
  short8 qf[2];
  {
    const unsigned short* qrow =
        qkB + (size_t)(b * S_ + q0 + qsub * 32 + l31) * 2048 + h * 64 + sw * 32;
#pragma unroll
    for (int cs = 0; cs < 2; cs++)
      qf[cs] = *(const short8*)(qrow + cs * 16 + hi * 8);
  }

  floatx16 accO[2];
#pragma unroll
  for (int n = 0; n < 2; n++) accO[n] = (floatx16)0.0f;
  float lsum = 0.f;
  const floatx16 zero16 = (floatx16)0.0f;

  const int srow = tid >> 3;   // 512 threads cover all 64 rows in one round
  const int scol = tid & 7;    // physical 16B chunk this lane fills
  const size_t kgbase = (size_t)(b * S_) * 2048 + 1024 + h * 64;
  const size_t vgbase = (size_t)h * 64 * 4096 + b * 2048;

  // stage tile t into buffer buf: 1 K + 1 V gl_lds per thread
#define STAGE(t_, buf_)                                                        \
  {                                                                            \
    const size_t kg_ = kgbase + (size_t)(t_) * 64 * 2048;                      \
    const size_t vg_ = vgbase + (size_t)(t_) * 64;                             \
    const int cl_ = scol ^ (srow & 7);                                         \
    gl_lds16(qkB + kg_ + (size_t)srow * 2048 + cl_ * 8,                        \
             &KV[buf_][0][(wave * 8) * 64]);                                   \
    gl_lds16(vTB + vg_ + (size_t)srow * 4096 + cl_ * 8,                        \
             &KV[buf_][1][(wave * 8) * 64]);                                   \
  }

  // prologue: stage tile 0 into buffer 0
  STAGE(0, 0);
  __syncthreads();

  int cur = 0;
  for (int t = 0; t < S_ / 64; t++) {
    if (t < S_ / 64 - 1) STAGE(t + 1, cur ^ 1);   // async prefetch
    const unsigned short* Kc = &KV[cur][0][0];
    const unsigned short* Vc = &KV[cur][1][0];

#pragma unroll
    for (int kb = 0; kb < 2; kb++) {
      const int krow = kb * 32 + l31;
      const int kx = krow & 7;
      floatx16 accS = zero16;
      __builtin_amdgcn_s_setprio(1);
#pragma unroll
      for (int cs = 0; cs < 2; cs++) {
        const int pc = (sw * 4 + cs * 2 + hi) ^ kx;
        const short8 kf = *(const short8*)(Kc + krow * 64 + pc * 8);
        accS = __builtin_amdgcn_mfma_f32_32x32x16_bf16(kf, qf[cs], accS, 0, 0, 0);
      }
      __builtin_amdgcn_s_setprio(0);
      // accS: q = l31 (col), k row = (reg&3) + 8*(reg>>2) + 4*hi
      unsigned w[8];
      float ls = 0.f;
#pragma unroll
      for (int i = 0; i < 8; i++) {
        float p0 = __expf(accS[2 * i] * 0.125f);
        float p1 = __expf(accS[2 * i + 1] * 0.125f);
        ls += p0 + p1;
        asm("v_cvt_pk_bf16_f32 %0, %1, %2" : "=v"(w[i]) : "v"(p0), "v"(p1));
      }
      lsum += ls;
      // dst.hi <-> src.lo: dst = low k-quad pack, src = high k-quad pack
      asm volatile("v_permlane32_swap_b32 %0, %1" : "+v"(w[0]), "+v"(w[2]));
      asm volatile("v_permlane32_swap_b32 %0, %1" : "+v"(w[1]), "+v"(w[3]));
      asm volatile("v_permlane32_swap_b32 %0, %1" : "+v"(w[4]), "+v"(w[6]));
      asm volatile("v_permlane32_swap_b32 %0, %1" : "+v"(w[5]), "+v"(w[7]));
      uint4 u0 = make_uint4(w[0], w[1], w[2], w[3]);
      uint4 u1 = make_uint4(w[4], w[5], w[6], w[7]);
      short8 pf0 = __builtin_bit_cast(short8, u0);
      short8 pf1 = __builtin_bit_cast(short8, u1);
      // PV for MY branch over this kb
      __builtin_amdgcn_s_setprio(1);
#pragma unroll
      for (int ks2 = 0; ks2 < 2; ks2++) {
        const short8 pa = ks2 ? pf1 : pf0;
#pragma unroll
        for (int n = 0; n < 2; n++) {
          const int vrow = n * 32 + l31;
          const int pc = (kb * 4 + ks2 * 2 + hi) ^ (vrow & 7);
          const short8 vf = *(const short8*)(Vc + vrow * 64 + pc * 8);
          accO[n] = __builtin_amdgcn_mfma_f32_32x32x16_bf16(pa, vf, accO[n], 0, 0, 0);
        }
      }
      __builtin_amdgcn_s_setprio(0);
    }
    __syncthreads();   // drains vmcnt(0): next tile staged; cur free to overwrite
    cur ^= 1;
  }
#undef STAGE

  // finalize row sums (partner lane-half holds complementary k rows)
  lsum += __shfl_xor(lsum, 32, 64);

  // ---- index-matched exchange: sw=1 pushes partials, sw=0 combines ----
  float* LF = (float*)&KV[0][0][0];   // 8192 floats = the dead K/V buffers
  if (sw == 1) {
    Lex[qsub][lane] = lsum;
#pragma unroll
    for (int n = 0; n < 2; n++)
#pragma unroll
      for (int r = 0; r < 16; r++)
        LF[qsub * 2048 + (n * 16 + r) * 64 + lane] = accO[n][r];
  }
  __syncthreads();

  if (sw == 0) {
    const float ls2v = Lex[qsub][lane];
    const float* nw = norm_w + h * HD_;
    const float nw0 = nw[l31], nw1 = nw[32 + l31];
#pragma unroll
    for (int r = 0; r < 16; r++) {
      const int qr = (r & 3) + 8 * (r >> 2) + 4 * hi;   // q row within wave's 32
      const float s1 = __shfl(lsum, qr, 64);
      const float s2 = __shfl(ls2v, qr, 64);
      const float inv1 = 1.0f / s1;
      const float c2 = lam / s2;
      const float b0 = LF[qsub * 2048 + (0 * 16 + r) * 64 + lane];
      const float b1 = LF[qsub * 2048 + (1 * 16 + r) * 64 + lane];
      float o0 = accO[0][r] * inv1 - b0 * c2;   // d = l31
      float o1 = accO[1][r] * inv1 - b1 * c2;   // d = 32 + l31
      float ss = o0 * o0 + o1 * o1;
#pragma unroll
      for (int msk = 1; msk <= 16; msk <<= 1) ss += __shfl_xor(ss, msk, 64);
      const float rsc = (1.0f - LAMBDA_INIT) * rsqrtf(ss * (1.0f / 64.0f) + EPS_);
      LF2[l31][qsub * 32 + qr] = o0 * rsc * nw0;        // fp32 staging (exact)
      LF2[32 + l31][qsub * 32 + qr] = o1 * rsc * nw1;
    }
  }
  __syncthreads();

  // ---- fused reshape: all 512 threads, d-major coalesced bf16 store ----
  // hidden[b*S*E + d*H*S + h*S + (q0 + qq)] = bf16(LF2[d][qq])
  {
    const int d = tid >> 3, g = tid & 7;
    unsigned short* dst =
        hid + (size_t)b * (S_ * E_) + (size_t)d * (H_ * S_) + h * S_ + q0 + g * 16;
    ushort8v v0, v1;
#pragma unroll
    for (int j = 0; j < 8; j++) {
      v0[j] = f2bf(LF2[d][g * 16 + j]);
      v1[j] = f2bf(LF2[d][g * 16 + 8 + j]);
    }
    *(ushort8v*)(dst) = v0;
    *(ushort8v*)(dst + 8) = v1;
  }
}

// ---------------------------------------------------------------------------
extern "C" void kernel_launch(void* const* d_in, const int* in_sizes, int n_in,
                              void* d_out, int out_size, void* d_ws, size_t ws_size,
                              hipStream_t stream) {
  const float* x = (const float*)d_in[0];
  const float* w_qkv = (const float*)d_in[1];
  const float* wo = (const float*)d_in[2];
  const float* lq1 = (const float*)d_in[3];
  const float* lq2 = (const float*)d_in[4];
  const float* lk1 = (const float*)d_in[5];
  const float* lk2 = (const float*)d_in[6];
  const float* norm_w = (const float*)d_in[7];
  float* out = (float*)d_out;

  unsigned short* xB = (unsigned short*)d_ws;             // 4096*1024
  unsigned short* WT = xB + (size_t)4096 * 1024;          // 3072*1024 (w_qkv^T)
  unsigned short* woT = WT + (size_t)3072 * 1024;         // 1024*1024
  unsigned short* qkB = woT + (size_t)1024 * 1024;        // 4096*2048
  unsigned short* vTB = qkB + (size_t)4096 * 2048;        // 1024*4096
  unsigned short* hidB = vTB + (size_t)1024 * 4096;       // 4096*1024

  // 0) fused bf16 cast + transposes of inputs (one launch)
  prep<<<2048, 256, 0, stream>>>(x, w_qkv, wo, xB, WT, woT);

  // 1) MERGED: {q,k = x @ Wqk -> qkB} + {vT = Wv^T @ x^T -> vTB} (1024 blocks,
  //    now 4 blocks/CU co-resident with BK=32 dbuf)
  qkv_gemm<<<1024, 256, 0, stream>>>(xB, WT, qkB, vTB);

  // 2) MFMA differential flash attention + RMSNorm + fused reshape -> hidB bf16
  flash_attn_mfma<<<B_ * H_ * (S_ / 128), 512, 0, stream>>>(qkB, vTB, lq1, lq2, lk1,
                                                            lk2, norm_w, hidB);
  // 3) out = hidden @ wo (fp32 out)  (128x64 tile: 512 blocks, 2 blocks/CU)
  gemm_bt<false, 64><<<dim3(1024 / 64, 4096 / 128), 256, 0, stream>>>(
      hidB, woT, (void*)out, 4096, 1024, 1024);
}

// Round 14
// 222.411 us; speedup vs baseline: 1.0203x; 1.0203x over previous
//
#include <hip/hip_runtime.h>
#include <math.h>

#define B_ 2
#define S_ 2048
#define E_ 1024
#define H_ 16
#define HD_ 64
#define LAMBDA_INIT 0.8f
#define EPS_ 1e-6f

typedef __attribute__((ext_vector_type(8))) short short8;   // 8 bf16 (4 VGPRs)
typedef __attribute__((ext_vector_type(8))) unsigned short ushort8v;
typedef __attribute__((ext_vector_type(4))) float floatx4;  // MFMA C/D 16x16
typedef __attribute__((ext_vector_type(16))) float floatx16; // MFMA C/D 32x32

__device__ __forceinline__ unsigned short f2bf(float f) {
  unsigned u = __float_as_uint(f);
  u += 0x7FFFu + ((u >> 16) & 1u);   // RNE
  return (unsigned short)(u >> 16);
}

__device__ __forceinline__ void gl_lds16(const void* g, void* l) {
  __builtin_amdgcn_global_load_lds((const __attribute__((address_space(1))) void*)g,
                                   (__attribute__((address_space(3))) void*)l,
                                   16, 0, 0);
}

// ---------------------------------------------------------------------------
// prep: fused {cast x -> bf16} + {transpose_cast w_qkv} + {transpose_cast wo}.
// [Byte-identical to verified R10.]
// ---------------------------------------------------------------------------
__global__ __launch_bounds__(256) void prep(const float* __restrict__ x,
                                            const float* __restrict__ w_qkv,
                                            const float* __restrict__ wo,
                                            unsigned short* __restrict__ xB,
                                            unsigned short* __restrict__ WT,
                                            unsigned short* __restrict__ woT) {
  __shared__ float tile[64][65];
  const int tid = threadIdx.x;
  const int bid = blockIdx.x;
  if (bid < 1024) {
    const int n4 = 4096 * 1024 / 4;
    for (int i = bid * 256 + tid; i < n4; i += 1024 * 256) {
      float4 v = ((const float4*)x)[i];
      ushort4 w;
      w.x = f2bf(v.x); w.y = f2bf(v.y); w.z = f2bf(v.z); w.w = f2bf(v.w);
      ((ushort4*)xB)[i] = w;
    }
    return;
  }
  const float* in;
  unsigned short* out;
  int R, C, bx, by;
  if (bid < 1792) {
    in = w_qkv; out = WT; R = 1024; C = 3072;
    int t = bid - 1024; bx = t % 48; by = t / 48;
  } else {
    in = wo; out = woT; R = 1024; C = 1024;
    int t = bid - 1792; bx = t % 16; by = t / 16;
  }
  const int c0 = bx * 64;
  const int r0 = by * 64;
#pragma unroll
  for (int it = 0; it < 16; it++) {
    int e = tid + it * 256;
    int rr = e >> 6, cc = e & 63;
    tile[rr][cc] = in[(size_t)(r0 + rr) * C + c0 + cc];
  }
  __syncthreads();
#pragma unroll
  for (int it = 0; it < 16; it++) {
    int e = tid + it * 256;
    int rr = e >> 6, cc = e & 63;
    out[(size_t)(c0 + rr) * R + r0 + cc] = f2bf(tile[cc][rr]);
  }
}

// ---------------------------------------------------------------------------
// bf16 MFMA GEMM body: [Byte-revert to verified R12: BK=64, 1-barrier
// double-buffer pipeline.] R13's BK=32 regressed (+7.5 us: 2x barrier/staging
// frequency outweighed the occupancy gain) -- GEMM structure is now FROZEN.
// ---------------------------------------------------------------------------
template <bool BF16OUT, int BNT>
__device__ __forceinline__ void gemm_body(unsigned short* AsB, unsigned short* BsB,
                                          const unsigned short* __restrict__ A,
                                          const unsigned short* __restrict__ Bt,
                                          void* __restrict__ C, int M, int N, int K,
                                          int bx, int by) {
  const int tid = threadIdx.x;
  const int wave = tid >> 6, lane = tid & 63;
  const int lane15 = lane & 15, quad = lane >> 4;
  const int m0 = by * 128;
  const int n0 = bx * BNT;
  const int wm = (wave & 1) * 64, wn = (wave >> 1) * (BNT / 2);
  const int NI = BNT / 32;   // n-fragments per wave

  floatx4 acc[4][NI];
#pragma unroll
  for (int mi = 0; mi < 4; mi++)
#pragma unroll
    for (int ni = 0; ni < NI; ni++) acc[mi][ni] = (floatx4)0.0f;

  const int rsA = wave * 32 + (lane >> 3);        // A staging row base (+j*8)
  const int rsB = wave * (BNT / 4) + (lane >> 3); // B staging row base (+j*8)
  const int cph = lane & 7;                       // physical chunk this lane fills

#define GSTAGE(k0_, As_, Bs_)                                                  \
  {                                                                            \
    _Pragma("unroll")                                                          \
    for (int j = 0; j < 4; j++) {                                              \
      int r = rsA + j * 8;                                                     \
      int cl = cph ^ (r & 7);                                                  \
      gl_lds16(A + (size_t)(m0 + r) * K + (k0_) + cl * 8,                      \
               (As_) + (wave * 32 + j * 8) * 64);                              \
    }                                                                          \
    _Pragma("unroll")                                                          \
    for (int j = 0; j < BNT / 32; j++) {                                       \
      int r = rsB + j * 8;                                                     \
      int cl = cph ^ (r & 7);                                                  \
      gl_lds16(Bt + (size_t)(n0 + r) * K + (k0_) + cl * 8,                     \
               (Bs_) + (wave * (BNT / 4) + j * 8) * 64);                       \
    }                                                                          \
  }

  // prologue: stage k-tile 0 into buffer 0 (__syncthreads drains vmcnt(0))
  GSTAGE(0, AsB, BsB);
  __syncthreads();

  int cur = 0;
  for (int k0 = 0; k0 < K; k0 += 64) {
    if (k0 + 64 < K)
      GSTAGE(k0 + 64, AsB + (cur ^ 1) * (128 * 64), BsB + (cur ^ 1) * (BNT * 64));
    const unsigned short* As = AsB + cur * (128 * 64);
    const unsigned short* Bs = BsB + cur * (BNT * 64);

#pragma unroll
    for (int ks = 0; ks < 2; ks++) {
      short8 af[4], bf[NI];
#pragma unroll
      for (int mi = 0; mi < 4; mi++) {
        int r = wm + mi * 16 + lane15;
        int phys = (ks * 4 + quad) ^ (r & 7);
        af[mi] = *(const short8*)(&As[r * 64 + phys * 8]);
      }
#pragma unroll
      for (int ni = 0; ni < NI; ni++) {
        int r = wn + ni * 16 + lane15;
        int phys = (ks * 4 + quad) ^ (r & 7);
        bf[ni] = *(const short8*)(&Bs[r * 64 + phys * 8]);
      }
#pragma unroll
      for (int mi = 0; mi < 4; mi++)
#pragma unroll
        for (int ni = 0; ni < NI; ni++)
          acc[mi][ni] = __builtin_amdgcn_mfma_f32_16x16x32_bf16(af[mi], bf[ni],
                                                                acc[mi][ni], 0, 0, 0);
    }
    __syncthreads();   // drains vmcnt(0): next tile staged; cur reads done
    cur ^= 1;
  }
#undef GSTAGE

#pragma unroll
  for (int mi = 0; mi < 4; mi++)
#pragma unroll
    for (int ni = 0; ni < NI; ni++)
#pragma unroll
      for (int reg = 0; reg < 4; reg++) {
        int row = m0 + wm + mi * 16 + quad * 4 + reg;
        int col = n0 + wn + ni * 16 + lane15;
        float v = acc[mi][ni][reg];
        if (BF16OUT)
          ((unsigned short*)C)[(size_t)row * N + col] = f2bf(v);
        else
          ((float*)C)[(size_t)row * N + col] = v;
      }
}

template <bool BF16OUT, int BNT>
__global__ __launch_bounds__(256, BNT == 64 ? 2 : 1) void gemm_bt(
    const unsigned short* __restrict__ A, const unsigned short* __restrict__ Bt,
    void* __restrict__ C, int M, int N, int K) {
  __shared__ __align__(16) unsigned short As[2 * 128 * 64];
  __shared__ __align__(16) unsigned short Bs[2 * BNT * 64];
  gemm_body<BF16OUT, BNT>(As, Bs, A, Bt, C, M, N, K, blockIdx.x, blockIdx.y);
}

__global__ __launch_bounds__(256) void qkv_gemm(const unsigned short* __restrict__ xB,
                                                const unsigned short* __restrict__ WT,
                                                unsigned short* __restrict__ qkB,
                                                unsigned short* __restrict__ vTB) {
  __shared__ __align__(16) unsigned short As[2 * 128 * 64];
  __shared__ __align__(16) unsigned short Bs[2 * 128 * 64];
  const int id = blockIdx.x;
  if (id < 512) {
    gemm_body<true, 128>(As, Bs, xB, WT, qkB, 4096, 2048, 1024, id & 15, id >> 4);
  } else {
    const int t = id - 512;
    gemm_body<true, 64>(As, Bs, WT + (size_t)2048 * 1024, xB, vTB, 1024, 4096, 1024,
                        t & 63, t >> 6);
  }
}

// ---------------------------------------------------------------------------
// MFMA flash differential attention, 32x32x16 swapped-QK^T, SPLIT-S waves.
// [Structure byte-identical to verified R12: no setprio (R13 A/B: null).]
// CHANGED (R14, single numerics-local delta): exp folded --
// __expf(s*0.125) [v_mul x0.125 -> v_mul xlog2e -> v_exp] becomes
// exp2(s * 0.18033688) [one v_mul -> v_exp]: saves 32 dependent v_mul per
// wave-iteration in the serial exp chain. One fewer rounding step.
// NOTE: split-kb (R3, R11) failed correctness twice; axis retired.
// ---------------------------------------------------------------------------
__global__ __launch_bounds__(512, 4) void flash_attn_mfma(
    const unsigned short* __restrict__ qkB, const unsigned short* __restrict__ vTB,
    const float* __restrict__ lq1, const float* __restrict__ lq2,
    const float* __restrict__ lk1, const float* __restrict__ lk2,
    const float* __restrict__ norm_w, unsigned short* __restrict__ hid) {
  __shared__ __align__(16) unsigned short KV[2][2][64 * 64];   // [buf][0=K,1=V]
  __shared__ float Lex[4][64];                                 // sw=1 lsum
  __shared__ float LF2[64][130];                               // [d][q] out tile

  const int tid = threadIdx.x;
  const int wave = tid >> 6, lane = tid & 63;
  const int l31 = lane & 31, hi = lane >> 5;
  const int qsub = wave >> 1, sw = wave & 1;

  // bijective XCD swizzle: the 16 q-tiles sharing one (b,h)'s K/V land on one XCD
  const int bid = (blockIdx.x & 7) * 64 + (blockIdx.x >> 3);   // 512 blocks
  const int qt = bid & 15;
  const int h = (bid >> 4) & 15;
  const int b = bid >> 8;
  const int q0 = qt * 128;

  float a1 = 0.f, a2 = 0.f;
  for (int d = 0; d < HD_; d++) {
    a1 += lq1[d] * lk1[d];
    a2 += lq2[d] * lk2[d];
  }
  const float lam = __expf(a1) - __expf(a2) + LAMBDA_INIT;

  // Q fragments for MY branch: Q[q = q0+qsub*32+l31][h*64 + sw*32 + cs*16 + hi*8]
  short8 qf[2];
  {
    const unsigned short* qrow =
        qkB + (size_t)(b * S_ + q0 + qsub * 32 + l31) * 2048 + h * 64 + sw * 32;
#pragma unroll
    for (int cs = 0; cs < 2; cs++)
      qf[cs] = *(const short8*)(qrow + cs * 16 + hi * 8);
  }

  floatx16 accO[2];
#pragma unroll
  for (int n = 0; n < 2; n++) accO[n] = (floatx16)0.0f;
  float lsum = 0.f;
  const floatx16 zero16 = (floatx16)0.0f;

  const int srow = tid >> 3;   // 512 threads cover all 64 rows in one round
  const int scol = tid & 7;    // physical 16B chunk this lane fills
  const size_t kgbase = (size_t)(b * S_) * 2048 + 1024 + h * 64;
  const size_t vgbase = (size_t)h * 64 * 4096 + b * 2048;

  // stage tile t into buffer buf: 1 K + 1 V gl_lds per thread
#define STAGE(t_, buf_)                                                        \
  {                                                                            \
    const size_t kg_ = kgbase + (size_t)(t_) * 64 * 2048;                      \
    const size_t vg_ = vgbase + (size_t)(t_) * 64;                             \
    const int cl_ = scol ^ (srow & 7);                                         \
    gl_lds16(qkB + kg_ + (size_t)srow * 2048 + cl_ * 8,                        \
             &KV[buf_][0][(wave * 8) * 64]);                                   \
    gl_lds16(vTB + vg_ + (size_t)srow * 4096 + cl_ * 8,                        \
             &KV[buf_][1][(wave * 8) * 64]);                                   \
  }

  // prologue: stage tile 0 into buffer 0
  STAGE(0, 0);
  __syncthreads();

  int cur = 0;
  for (int t = 0; t < S_ / 64; t++) {
    if (t < S_ / 64 - 1) STAGE(t + 1, cur ^ 1);   // async prefetch
    const unsigned short* Kc = &KV[cur][0][0];
    const unsigned short* Vc = &KV[cur][1][0];

#pragma unroll
    for (int kb = 0; kb < 2; kb++) {
      const int krow = kb * 32 + l31;
      const int kx = krow & 7;
      floatx16 accS = zero16;
#pragma unroll
      for (int cs = 0; cs < 2; cs++) {
        const int pc = (sw * 4 + cs * 2 + hi) ^ kx;
        const short8 kf = *(const short8*)(Kc + krow * 64 + pc * 8);
        accS = __builtin_amdgcn_mfma_f32_32x32x16_bf16(kf, qf[cs], accS, 0, 0, 0);
      }
      // accS: q = l31 (col), k row = (reg&3) + 8*(reg>>2) + 4*hi
      unsigned w[8];
      float ls = 0.f;
#pragma unroll
      for (int i = 0; i < 8; i++) {
        float p0 = __builtin_amdgcn_exp2f(accS[2 * i] * 0.18033688f);
        float p1 = __builtin_amdgcn_exp2f(accS[2 * i + 1] * 0.18033688f);
        ls += p0 + p1;
        asm("v_cvt_pk_bf16_f32 %0, %1, %2" : "=v"(w[i]) : "v"(p0), "v"(p1));
      }
      lsum += ls;
      // dst.hi <-> src.lo: dst = low k-quad pack, src = high k-quad pack
      asm volatile("v_permlane32_swap_b32 %0, %1" : "+v"(w[0]), "+v"(w[2]));
      asm volatile("v_permlane32_swap_b32 %0, %1" : "+v"(w[1]), "+v"(w[3]));
      asm volatile("v_permlane32_swap_b32 %0, %1" : "+v"(w[4]), "+v"(w[6]));
      asm volatile("v_permlane32_swap_b32 %0, %1" : "+v"(w[5]), "+v"(w[7]));
      uint4 u0 = make_uint4(w[0], w[1], w[2], w[3]);
      uint4 u1 = make_uint4(w[4], w[5], w[6], w[7]);
      short8 pf0 = __builtin_bit_cast(short8, u0);
      short8 pf1 = __builtin_bit_cast(short8, u1);
      // PV for MY branch over this kb
#pragma unroll
      for (int ks2 = 0; ks2 < 2; ks2++) {
        const short8 pa = ks2 ? pf1 : pf0;
#pragma unroll
        for (int n = 0; n < 2; n++) {
          const int vrow = n * 32 + l31;
          const int pc = (kb * 4 + ks2 * 2 + hi) ^ (vrow & 7);
          const short8 vf = *(const short8*)(Vc + vrow * 64 + pc * 8);
          accO[n] = __builtin_amdgcn_mfma_f32_32x32x16_bf16(pa, vf, accO[n], 0, 0, 0);
        }
      }
    }
    __syncthreads();   // drains vmcnt(0): next tile staged; cur free to overwrite
    cur ^= 1;
  }
#undef STAGE

  // finalize row sums (partner lane-half holds complementary k rows)
  lsum += __shfl_xor(lsum, 32, 64);

  // ---- index-matched exchange: sw=1 pushes partials, sw=0 combines ----
  float* LF = (float*)&KV[0][0][0];   // 8192 floats = the dead K/V buffers
  if (sw == 1) {
    Lex[qsub][lane] = lsum;
#pragma unroll
    for (int n = 0; n < 2; n++)
#pragma unroll
      for (int r = 0; r < 16; r++)
        LF[qsub * 2048 + (n * 16 + r) * 64 + lane] = accO[n][r];
  }
  __syncthreads();

  if (sw == 0) {
    const float ls2v = Lex[qsub][lane];
    const float* nw = norm_w + h * HD_;
    const float nw0 = nw[l31], nw1 = nw[32 + l31];
#pragma unroll
    for (int r = 0; r < 16; r++) {
      const int qr = (r & 3) + 8 * (r >> 2) + 4 * hi;   // q row within wave's 32
      const float s1 = __shfl(lsum, qr, 64);
      const float s2 = __shfl(ls2v, qr, 64);
      const float inv1 = 1.0f / s1;
      const float c2 = lam / s2;
      const float b0 = LF[qsub * 2048 + (0 * 16 + r) * 64 + lane];
      const float b1 = LF[qsub * 2048 + (1 * 16 + r) * 64 + lane];
      float o0 = accO[0][r] * inv1 - b0 * c2;   // d = l31
      float o1 = accO[1][r] * inv1 - b1 * c2;   // d = 32 + l31
      float ss = o0 * o0 + o1 * o1;
#pragma unroll
      for (int msk = 1; msk <= 16; msk <<= 1) ss += __shfl_xor(ss, msk, 64);
      const float rsc = (1.0f - LAMBDA_INIT) * rsqrtf(ss * (1.0f / 64.0f) + EPS_);
      LF2[l31][qsub * 32 + qr] = o0 * rsc * nw0;        // fp32 staging (exact)
      LF2[32 + l31][qsub * 32 + qr] = o1 * rsc * nw1;
    }
  }
  __syncthreads();

  // ---- fused reshape: all 512 threads, d-major coalesced bf16 store ----
  // hidden[b*S*E + d*H*S + h*S + (q0 + qq)] = bf16(LF2[d][qq])
  {
    const int d = tid >> 3, g = tid & 7;
    unsigned short* dst =
        hid + (size_t)b * (S_ * E_) + (size_t)d * (H_ * S_) + h * S_ + q0 + g * 16;
    ushort8v v0, v1;
#pragma unroll
    for (int j = 0; j < 8; j++) {
      v0[j] = f2bf(LF2[d][g * 16 + j]);
      v1[j] = f2bf(LF2[d][g * 16 + 8 + j]);
    }
    *(ushort8v*)(dst) = v0;
    *(ushort8v*)(dst + 8) = v1;
  }
}

// ---------------------------------------------------------------------------
extern "C" void kernel_launch(void* const* d_in, const int* in_sizes, int n_in,
                              void* d_out, int out_size, void* d_ws, size_t ws_size,
                              hipStream_t stream) {
  const float* x = (const float*)d_in[0];
  const float* w_qkv = (const float*)d_in[1];
  const float* wo = (const float*)d_in[2];
  const float* lq1 = (const float*)d_in[3];
  const float* lq2 = (const float*)d_in[4];
  const float* lk1 = (const float*)d_in[5];
  const float* lk2 = (const float*)d_in[6];
  const float* norm_w = (const float*)d_in[7];
  float* out = (float*)d_out;

  unsigned short* xB = (unsigned short*)d_ws;             // 4096*1024
  unsigned short* WT = xB + (size_t)4096 * 1024;          // 3072*1024 (w_qkv^T)
  unsigned short* woT = WT + (size_t)3072 * 1024;         // 1024*1024
  unsigned short* qkB = woT + (size_t)1024 * 1024;        // 4096*2048
  unsigned short* vTB = qkB + (size_t)4096 * 2048;        // 1024*4096
  unsigned short* hidB = vTB + (size_t)1024 * 4096;       // 4096*1024

  // 0) fused bf16 cast + transposes of inputs (one launch)
  prep<<<2048, 256, 0, stream>>>(x, w_qkv, wo, xB, WT, woT);

  // 1) MERGED: {q,k = x @ Wqk -> qkB} + {vT = Wv^T @ x^T -> vTB} (1024 blocks)
  qkv_gemm<<<1024, 256, 0, stream>>>(xB, WT, qkB, vTB);

  // 2) MFMA differential flash attention + RMSNorm + fused reshape -> hidB bf16
  flash_attn_mfma<<<B_ * H_ * (S_ / 128), 512, 0, stream>>>(qkB, vTB, lq1, lq2, lk1,
                                                            lk2, norm_w, hidB);
  // 3) out = hidden @ wo (fp32 out)  (128x64 tile: 512 blocks, 2 blocks/CU)
  gemm_bt<false, 64><<<dim3(1024 / 64, 4096 / 128), 256, 0, stream>>>(
      hidB, woT, (void*)out, 4096, 1024, 1024);
}

// Round 15
// 219.481 us; speedup vs baseline: 1.0339x; 1.0133x over previous
//
#include <hip/hip_runtime.h>
#include <math.h>

#define B_ 2
#define S_ 2048
#define E_ 1024
#define H_ 16
#define HD_ 64
#define LAMBDA_INIT 0.8f
#define EPS_ 1e-6f

typedef __attribute__((ext_vector_type(8))) short short8;   // 8 bf16 (4 VGPRs)
typedef __attribute__((ext_vector_type(8))) unsigned short ushort8v;
typedef __attribute__((ext_vector_type(4))) float floatx4;  // MFMA C/D 16x16
typedef __attribute__((ext_vector_type(16))) float floatx16; // MFMA C/D 32x32

__device__ __forceinline__ unsigned short f2bf(float f) {
  unsigned u = __float_as_uint(f);
  u += 0x7FFFu + ((u >> 16) & 1u);   // RNE
  return (unsigned short)(u >> 16);
}

__device__ __forceinline__ void gl_lds16(const void* g, void* l) {
  __builtin_amdgcn_global_load_lds((const __attribute__((address_space(1))) void*)g,
                                   (__attribute__((address_space(3))) void*)l,
                                   16, 0, 0);
}

// ---------------------------------------------------------------------------
// prep: fused {cast x -> bf16} + {transpose_cast w_qkv} + {transpose_cast wo}.
// [Byte-identical to verified R10.]
// ---------------------------------------------------------------------------
__global__ __launch_bounds__(256) void prep(const float* __restrict__ x,
                                            const float* __restrict__ w_qkv,
                                            const float* __restrict__ wo,
                                            unsigned short* __restrict__ xB,
                                            unsigned short* __restrict__ WT,
                                            unsigned short* __restrict__ woT) {
  __shared__ float tile[64][65];
  const int tid = threadIdx.x;
  const int bid = blockIdx.x;
  if (bid < 1024) {
    const int n4 = 4096 * 1024 / 4;
    for (int i = bid * 256 + tid; i < n4; i += 1024 * 256) {
      float4 v = ((const float4*)x)[i];
      ushort4 w;
      w.x = f2bf(v.x); w.y = f2bf(v.y); w.z = f2bf(v.z); w.w = f2bf(v.w);
      ((ushort4*)xB)[i] = w;
    }
    return;
  }
  const float* in;
  unsigned short* out;
  int R, C, bx, by;
  if (bid < 1792) {
    in = w_qkv; out = WT; R = 1024; C = 3072;
    int t = bid - 1024; bx = t % 48; by = t / 48;
  } else {
    in = wo; out = woT; R = 1024; C = 1024;
    int t = bid - 1792; bx = t % 16; by = t / 16;
  }
  const int c0 = bx * 64;
  const int r0 = by * 64;
#pragma unroll
  for (int it = 0; it < 16; it++) {
    int e = tid + it * 256;
    int rr = e >> 6, cc = e & 63;
    tile[rr][cc] = in[(size_t)(r0 + rr) * C + c0 + cc];
  }
  __syncthreads();
#pragma unroll
  for (int it = 0; it < 16; it++) {
    int e = tid + it * 256;
    int rr = e >> 6, cc = e & 63;
    out[(size_t)(c0 + rr) * R + r0 + cc] = f2bf(tile[cc][rr]);
  }
}

// ---------------------------------------------------------------------------
// bf16 MFMA GEMM body: [Byte-identical to verified R12: BK=64, 1-barrier
// double-buffer pipeline. GEMM structure FROZEN: merge neutral (R10), dbuf
// +6.6us (R12), BK=32 -7.5us (R13).]
// ---------------------------------------------------------------------------
template <bool BF16OUT, int BNT>
__device__ __forceinline__ void gemm_body(unsigned short* AsB, unsigned short* BsB,
                                          const unsigned short* __restrict__ A,
                                          const unsigned short* __restrict__ Bt,
                                          void* __restrict__ C, int M, int N, int K,
                                          int bx, int by) {
  const int tid = threadIdx.x;
  const int wave = tid >> 6, lane = tid & 63;
  const int lane15 = lane & 15, quad = lane >> 4;
  const int m0 = by * 128;
  const int n0 = bx * BNT;
  const int wm = (wave & 1) * 64, wn = (wave >> 1) * (BNT / 2);
  const int NI = BNT / 32;   // n-fragments per wave

  floatx4 acc[4][NI];
#pragma unroll
  for (int mi = 0; mi < 4; mi++)
#pragma unroll
    for (int ni = 0; ni < NI; ni++) acc[mi][ni] = (floatx4)0.0f;

  const int rsA = wave * 32 + (lane >> 3);        // A staging row base (+j*8)
  const int rsB = wave * (BNT / 4) + (lane >> 3); // B staging row base (+j*8)
  const int cph = lane & 7;                       // physical chunk this lane fills

#define GSTAGE(k0_, As_, Bs_)                                                  \
  {                                                                            \
    _Pragma("unroll")                                                          \
    for (int j = 0; j < 4; j++) {                                              \
      int r = rsA + j * 8;                                                     \
      int cl = cph ^ (r & 7);                                                  \
      gl_lds16(A + (size_t)(m0 + r) * K + (k0_) + cl * 8,                      \
               (As_) + (wave * 32 + j * 8) * 64);                              \
    }                                                                          \
    _Pragma("unroll")                                                          \
    for (int j = 0; j < BNT / 32; j++) {                                       \
      int r = rsB + j * 8;                                                     \
      int cl = cph ^ (r & 7);                                                  \
      gl_lds16(Bt + (size_t)(n0 + r) * K + (k0_) + cl * 8,                     \
               (Bs_) + (wave * (BNT / 4) + j * 8) * 64);                       \
    }                                                                          \
  }

  // prologue: stage k-tile 0 into buffer 0 (__syncthreads drains vmcnt(0))
  GSTAGE(0, AsB, BsB);
  __syncthreads();

  int cur = 0;
  for (int k0 = 0; k0 < K; k0 += 64) {
    if (k0 + 64 < K)
      GSTAGE(k0 + 64, AsB + (cur ^ 1) * (128 * 64), BsB + (cur ^ 1) * (BNT * 64));
    const unsigned short* As = AsB + cur * (128 * 64);
    const unsigned short* Bs = BsB + cur * (BNT * 64);

#pragma unroll
    for (int ks = 0; ks < 2; ks++) {
      short8 af[4], bf[NI];
#pragma unroll
      for (int mi = 0; mi < 4; mi++) {
        int r = wm + mi * 16 + lane15;
        int phys = (ks * 4 + quad) ^ (r & 7);
        af[mi] = *(const short8*)(&As[r * 64 + phys * 8]);
      }
#pragma unroll
      for (int ni = 0; ni < NI; ni++) {
        int r = wn + ni * 16 + lane15;
        int phys = (ks * 4 + quad) ^ (r & 7);
        bf[ni] = *(const short8*)(&Bs[r * 64 + phys * 8]);
      }
#pragma unroll
      for (int mi = 0; mi < 4; mi++)
#pragma unroll
        for (int ni = 0; ni < NI; ni++)
          acc[mi][ni] = __builtin_amdgcn_mfma_f32_16x16x32_bf16(af[mi], bf[ni],
                                                                acc[mi][ni], 0, 0, 0);
    }
    __syncthreads();   // drains vmcnt(0): next tile staged; cur reads done
    cur ^= 1;
  }
#undef GSTAGE

#pragma unroll
  for (int mi = 0; mi < 4; mi++)
#pragma unroll
    for (int ni = 0; ni < NI; ni++)
#pragma unroll
      for (int reg = 0; reg < 4; reg++) {
        int row = m0 + wm + mi * 16 + quad * 4 + reg;
        int col = n0 + wn + ni * 16 + lane15;
        float v = acc[mi][ni][reg];
        if (BF16OUT)
          ((unsigned short*)C)[(size_t)row * N + col] = f2bf(v);
        else
          ((float*)C)[(size_t)row * N + col] = v;
      }
}

template <bool BF16OUT, int BNT>
__global__ __launch_bounds__(256, BNT == 64 ? 2 : 1) void gemm_bt(
    const unsigned short* __restrict__ A, const unsigned short* __restrict__ Bt,
    void* __restrict__ C, int M, int N, int K) {
  __shared__ __align__(16) unsigned short As[2 * 128 * 64];
  __shared__ __align__(16) unsigned short Bs[2 * BNT * 64];
  gemm_body<BF16OUT, BNT>(As, Bs, A, Bt, C, M, N, K, blockIdx.x, blockIdx.y);
}

__global__ __launch_bounds__(256) void qkv_gemm(const unsigned short* __restrict__ xB,
                                                const unsigned short* __restrict__ WT,
                                                unsigned short* __restrict__ qkB,
                                                unsigned short* __restrict__ vTB) {
  __shared__ __align__(16) unsigned short As[2 * 128 * 64];
  __shared__ __align__(16) unsigned short Bs[2 * 128 * 64];
  const int id = blockIdx.x;
  if (id < 512) {
    gemm_body<true, 128>(As, Bs, xB, WT, qkB, 4096, 2048, 1024, id & 15, id >> 4);
  } else {
    const int t = id - 512;
    gemm_body<true, 64>(As, Bs, WT + (size_t)2048 * 1024, xB, vTB, 1024, 4096, 1024,
                        t & 63, t >> 6);
  }
}

// ---------------------------------------------------------------------------
// MFMA flash differential attention, 32x32x16 swapped-QK^T, SPLIT-S waves.
// [Main loop + exchange byte-identical to R14-verified (incl. exp2 fold).]
// CHANGED (R15, LDS diet): LF2 out-tile stored as ushort (f2bf applied at
// epilogue write instead of final copy -- bitwise-identical output bytes).
// LDS 67KB -> ~50KB -> 3 blocks/CU (was 2): more co-resident blocks to fill
// the lockstep latency gaps. Bank maps re-checked: writes (65*l31 + col/2)
// mod 32 distinct; reads (d + 8g) mod 32 <= 2-way (free).
// NOTE: split-kb (R3, R11) failed correctness twice; axis retired. setprio
// null (R13). GEMM frozen.
// ---------------------------------------------------------------------------
__global__ __launch_bounds__(512) void flash_attn_mfma(
    const unsigned short* __restrict__ qkB, const unsigned short* __restrict__ vTB,
    const float* __restrict__ lq1, const float* __restrict__ lq2,
    const float* __restrict__ lk1, const float* __restrict__ lk2,
    const float* __restrict__ norm_w, unsigned short* __restrict__ hid) {
  __shared__ __align__(16) unsigned short KV[2][2][64 * 64];   // [buf][0=K,1=V]
  __shared__ float Lex[4][64];                                 // sw=1 lsum
  __shared__ unsigned short LF2[64][130];                      // [d][q] bf16 out

  const int tid = threadIdx.x;
  const int wave = tid >> 6, lane = tid & 63;
  const int l31 = lane & 31, hi = lane >> 5;
  const int qsub = wave >> 1, sw = wave & 1;

  // bijective XCD swizzle: the 16 q-tiles sharing one (b,h)'s K/V land on one XCD
  const int bid = (blockIdx.x & 7) * 64 + (blockIdx.x >> 3);   // 512 blocks
  const int qt = bid & 15;
  const int h = (bid >> 4) & 15;
  const int b = bid >> 8;
  const int q0 = qt * 128;

  float a1 = 0.f, a2 = 0.f;
  for (int d = 0; d < HD_; d++) {
    a1 += lq1[d] * lk1[d];
    a2 += lq2[d] * lk2[d];
  }
  const float lam = __expf(a1) - __expf(a2) + LAMBDA_INIT;

  // Q fragments for MY branch: Q[q = q0+qsub*32+l31][h*64 + sw*32 + cs*16 + hi*8]
  short8 qf[2];
  {
    const unsigned short* qrow =
        qkB + (size_t)(b * S_ + q0 + qsub * 32 + l31) * 2048 + h * 64 + sw * 32;
#pragma unroll
    for (int cs = 0; cs < 2; cs++)
      qf[cs] = *(const short8*)(qrow + cs * 16 + hi * 8);
  }

  floatx16 accO[2];
#pragma unroll
  for (int n = 0; n < 2; n++) accO[n] = (floatx16)0.0f;
  float lsum = 0.f;
  const floatx16 zero16 = (floatx16)0.0f;

  const int srow = tid >> 3;   // 512 threads cover all 64 rows in one round
  const int scol = tid & 7;    // physical 16B chunk this lane fills
  const size_t kgbase = (size_t)(b * S_) * 2048 + 1024 + h * 64;
  const size_t vgbase = (size_t)h * 64 * 4096 + b * 2048;

  // stage tile t into buffer buf: 1 K + 1 V gl_lds per thread
#define STAGE(t_, buf_)                                                        \
  {                                                                            \
    const size_t kg_ = kgbase + (size_t)(t_) * 64 * 2048;                      \
    const size_t vg_ = vgbase + (size_t)(t_) * 64;                             \
    const int cl_ = scol ^ (srow & 7);                                         \
    gl_lds16(qkB + kg_ + (size_t)srow * 2048 + cl_ * 8,                        \
             &KV[buf_][0][(wave * 8) * 64]);                                   \
    gl_lds16(vTB + vg_ + (size_t)srow * 4096 + cl_ * 8,                        \
             &KV[buf_][1][(wave * 8) * 64]);                                   \
  }

  // prologue: stage tile 0 into buffer 0
  STAGE(0, 0);
  __syncthreads();

  int cur = 0;
  for (int t = 0; t < S_ / 64; t++) {
    if (t < S_ / 64 - 1) STAGE(t + 1, cur ^ 1);   // async prefetch
    const unsigned short* Kc = &KV[cur][0][0];
    const unsigned short* Vc = &KV[cur][1][0];

#pragma unroll
    for (int kb = 0; kb < 2; kb++) {
      const int krow = kb * 32 + l31;
      const int kx = krow & 7;
      floatx16 accS = zero16;
#pragma unroll
      for (int cs = 0; cs < 2; cs++) {
        const int pc = (sw * 4 + cs * 2 + hi) ^ kx;
        const short8 kf = *(const short8*)(Kc + krow * 64 + pc * 8);
        accS = __builtin_amdgcn_mfma_f32_32x32x16_bf16(kf, qf[cs], accS, 0, 0, 0);
      }
      // accS: q = l31 (col), k row = (reg&3) + 8*(reg>>2) + 4*hi
      unsigned w[8];
      float ls = 0.f;
#pragma unroll
      for (int i = 0; i < 8; i++) {
        float p0 = __builtin_amdgcn_exp2f(accS[2 * i] * 0.18033688f);
        float p1 = __builtin_amdgcn_exp2f(accS[2 * i + 1] * 0.18033688f);
        ls += p0 + p1;
        asm("v_cvt_pk_bf16_f32 %0, %1, %2" : "=v"(w[i]) : "v"(p0), "v"(p1));
      }
      lsum += ls;
      // dst.hi <-> src.lo: dst = low k-quad pack, src = high k-quad pack
      asm volatile("v_permlane32_swap_b32 %0, %1" : "+v"(w[0]), "+v"(w[2]));
      asm volatile("v_permlane32_swap_b32 %0, %1" : "+v"(w[1]), "+v"(w[3]));
      asm volatile("v_permlane32_swap_b32 %0, %1" : "+v"(w[4]), "+v"(w[6]));
      asm volatile("v_permlane32_swap_b32 %0, %1" : "+v"(w[5]), "+v"(w[7]));
      uint4 u0 = make_uint4(w[0], w[1], w[2], w[3]);
      uint4 u1 = make_uint4(w[4], w[5], w[6], w[7]);
      short8 pf0 = __builtin_bit_cast(short8, u0);
      short8 pf1 = __builtin_bit_cast(short8, u1);
      // PV for MY branch over this kb
#pragma unroll
      for (int ks2 = 0; ks2 < 2; ks2++) {
        const short8 pa = ks2 ? pf1 : pf0;
#pragma unroll
        for (int n = 0; n < 2; n++) {
          const int vrow = n * 32 + l31;
          const int pc = (kb * 4 + ks2 * 2 + hi) ^ (vrow & 7);
          const short8 vf = *(const short8*)(Vc + vrow * 64 + pc * 8);
          accO[n] = __builtin_amdgcn_mfma_f32_32x32x16_bf16(pa, vf, accO[n], 0, 0, 0);
        }
      }
    }
    __syncthreads();   // drains vmcnt(0): next tile staged; cur free to overwrite
    cur ^= 1;
  }
#undef STAGE

  // finalize row sums (partner lane-half holds complementary k rows)
  lsum += __shfl_xor(lsum, 32, 64);

  // ---- index-matched exchange: sw=1 pushes partials, sw=0 combines ----
  float* LF = (float*)&KV[0][0][0];   // 8192 floats = the dead K/V buffers
  if (sw == 1) {
    Lex[qsub][lane] = lsum;
#pragma unroll
    for (int n = 0; n < 2; n++)
#pragma unroll
      for (int r = 0; r < 16; r++)
        LF[qsub * 2048 + (n * 16 + r) * 64 + lane] = accO[n][r];
  }
  __syncthreads();

  if (sw == 0) {
    const float ls2v = Lex[qsub][lane];
    const float* nw = norm_w + h * HD_;
    const float nw0 = nw[l31], nw1 = nw[32 + l31];
#pragma unroll
    for (int r = 0; r < 16; r++) {
      const int qr = (r & 3) + 8 * (r >> 2) + 4 * hi;   // q row within wave's 32
      const float s1 = __shfl(lsum, qr, 64);
      const float s2 = __shfl(ls2v, qr, 64);
      const float inv1 = 1.0f / s1;
      const float c2 = lam / s2;
      const float b0 = LF[qsub * 2048 + (0 * 16 + r) * 64 + lane];
      const float b1 = LF[qsub * 2048 + (1 * 16 + r) * 64 + lane];
      float o0 = accO[0][r] * inv1 - b0 * c2;   // d = l31
      float o1 = accO[1][r] * inv1 - b1 * c2;   // d = 32 + l31
      float ss = o0 * o0 + o1 * o1;
#pragma unroll
      for (int msk = 1; msk <= 16; msk <<= 1) ss += __shfl_xor(ss, msk, 64);
      const float rsc = (1.0f - LAMBDA_INIT) * rsqrtf(ss * (1.0f / 64.0f) + EPS_);
      // bf16 conversion moved here (same values, same f2bf) -> bitwise-same out
      LF2[l31][qsub * 32 + qr] = f2bf(o0 * rsc * nw0);
      LF2[32 + l31][qsub * 32 + qr] = f2bf(o1 * rsc * nw1);
    }
  }
  __syncthreads();

  // ---- fused reshape: all 512 threads, d-major coalesced bf16 store ----
  // hidden[b*S*E + d*H*S + h*S + (q0 + qq)] = LF2[d][qq] (already bf16)
  {
    const int d = tid >> 3, g = tid & 7;
    unsigned short* dst =
        hid + (size_t)b * (S_ * E_) + (size_t)d * (H_ * S_) + h * S_ + q0 + g * 16;
    ushort8v v0, v1;
#pragma unroll
    for (int j = 0; j < 8; j++) {
      v0[j] = LF2[d][g * 16 + j];
      v1[j] = LF2[d][g * 16 + 8 + j];
    }
    *(ushort8v*)(dst) = v0;
    *(ushort8v*)(dst + 8) = v1;
  }
}

// ---------------------------------------------------------------------------
extern "C" void kernel_launch(void* const* d_in, const int* in_sizes, int n_in,
                              void* d_out, int out_size, void* d_ws, size_t ws_size,
                              hipStream_t stream) {
  const float* x = (const float*)d_in[0];
  const float* w_qkv = (const float*)d_in[1];
  const float* wo = (const float*)d_in[2];
  const float* lq1 = (const float*)d_in[3];
  const float* lq2 = (const float*)d_in[4];
  const float* lk1 = (const float*)d_in[5];
  const float* lk2 = (const float*)d_in[6];
  const float* norm_w = (const float*)d_in[7];
  float* out = (float*)d_out;

  unsigned short* xB = (unsigned short*)d_ws;             // 4096*1024
  unsigned short* WT = xB + (size_t)4096 * 1024;          // 3072*1024 (w_qkv^T)
  unsigned short* woT = WT + (size_t)3072 * 1024;         // 1024*1024
  unsigned short* qkB = woT + (size_t)1024 * 1024;        // 4096*2048
  unsigned short* vTB = qkB + (size_t)4096 * 2048;        // 1024*4096
  unsigned short* hidB = vTB + (size_t)1024 * 4096;       // 4096*1024

  // 0) fused bf16 cast + transposes of inputs (one launch)
  prep<<<2048, 256, 0, stream>>>(x, w_qkv, wo, xB, WT, woT);

  // 1) MERGED: {q,k = x @ Wqk -> qkB} + {vT = Wv^T @ x^T -> vTB} (1024 blocks)
  qkv_gemm<<<1024, 256, 0, stream>>>(xB, WT, qkB, vTB);

  // 2) MFMA differential flash attention + RMSNorm + fused reshape -> hidB bf16
  flash_attn_mfma<<<B_ * H_ * (S_ / 128), 512, 0, stream>>>(qkB, vTB, lq1, lq2, lk1,
                                                            lk2, norm_w, hidB);
  // 3) out = hidden @ wo (fp32 out)  (128x64 tile: 512 blocks, 2 blocks/CU)
  gemm_bt<false, 64><<<dim3(1024 / 64, 4096 / 128), 256, 0, stream>>>(
      hidB, woT, (void*)out, 4096, 1024, 1024);
}

// Round 17
// 216.393 us; speedup vs baseline: 1.0487x; 1.0143x over previous
//
#include <hip/hip_runtime.h>
#include <math.h>

#define B_ 2
#define S_ 2048
#define E_ 1024
#define H_ 16
#define HD_ 64
#define LAMBDA_INIT 0.8f
#define EPS_ 1e-6f

typedef __attribute__((ext_vector_type(8))) short short8;   // 8 bf16 (4 VGPRs)
typedef __attribute__((ext_vector_type(8))) unsigned short ushort8v;
typedef __attribute__((ext_vector_type(4))) float floatx4;  // MFMA C/D 16x16
typedef __attribute__((ext_vector_type(16))) float floatx16; // MFMA C/D 32x32

__device__ __forceinline__ unsigned short f2bf(float f) {
  unsigned u = __float_as_uint(f);
  u += 0x7FFFu + ((u >> 16) & 1u);   // RNE
  return (unsigned short)(u >> 16);
}

__device__ __forceinline__ void gl_lds16(const void* g, void* l) {
  __builtin_amdgcn_global_load_lds((const __attribute__((address_space(1))) void*)g,
                                   (__attribute__((address_space(3))) void*)l,
                                   16, 0, 0);
}

// ---------------------------------------------------------------------------
// prep: fused {cast x -> bf16} + {transpose_cast w_qkv} + {transpose_cast wo}.
// [Byte-identical to verified R10.]
// ---------------------------------------------------------------------------
__global__ __launch_bounds__(256) void prep(const float* __restrict__ x,
                                            const float* __restrict__ w_qkv,
                                            const float* __restrict__ wo,
                                            unsigned short* __restrict__ xB,
                                            unsigned short* __restrict__ WT,
                                            unsigned short* __restrict__ woT) {
  __shared__ float tile[64][65];
  const int tid = threadIdx.x;
  const int bid = blockIdx.x;
  if (bid < 1024) {
    const int n4 = 4096 * 1024 / 4;
    for (int i = bid * 256 + tid; i < n4; i += 1024 * 256) {
      float4 v = ((const float4*)x)[i];
      ushort4 w;
      w.x = f2bf(v.x); w.y = f2bf(v.y); w.z = f2bf(v.z); w.w = f2bf(v.w);
      ((ushort4*)xB)[i] = w;
    }
    return;
  }
  const float* in;
  unsigned short* out;
  int R, C, bx, by;
  if (bid < 1792) {
    in = w_qkv; out = WT; R = 1024; C = 3072;
    int t = bid - 1024; bx = t % 48; by = t / 48;
  } else {
    in = wo; out = woT; R = 1024; C = 1024;
    int t = bid - 1792; bx = t % 16; by = t / 16;
  }
  const int c0 = bx * 64;
  const int r0 = by * 64;
#pragma unroll
  for (int it = 0; it < 16; it++) {
    int e = tid + it * 256;
    int rr = e >> 6, cc = e & 63;
    tile[rr][cc] = in[(size_t)(r0 + rr) * C + c0 + cc];
  }
  __syncthreads();
#pragma unroll
  for (int it = 0; it < 16; it++) {
    int e = tid + it * 256;
    int rr = e >> 6, cc = e & 63;
    out[(size_t)(c0 + rr) * R + r0 + cc] = f2bf(tile[cc][rr]);
  }
}

// ---------------------------------------------------------------------------
// bf16 MFMA GEMM body: [Byte-identical to verified R12: BK=64, 1-barrier
// double-buffer pipeline. GEMM structure FROZEN: merge neutral (R10), dbuf
// +6.6us (R12), BK=32 -7.5us (R13).]
// ---------------------------------------------------------------------------
template <bool BF16OUT, int BNT>
__device__ __forceinline__ void gemm_body(unsigned short* AsB, unsigned short* BsB,
                                          const unsigned short* __restrict__ A,
                                          const unsigned short* __restrict__ Bt,
                                          void* __restrict__ C, int M, int N, int K,
                                          int bx, int by) {
  const int tid = threadIdx.x;
  const int wave = tid >> 6, lane = tid & 63;
  const int lane15 = lane & 15, quad = lane >> 4;
  const int m0 = by * 128;
  const int n0 = bx * BNT;
  const int wm = (wave & 1) * 64, wn = (wave >> 1) * (BNT / 2);
  const int NI = BNT / 32;   // n-fragments per wave

  floatx4 acc[4][NI];
#pragma unroll
  for (int mi = 0; mi < 4; mi++)
#pragma unroll
    for (int ni = 0; ni < NI; ni++) acc[mi][ni] = (floatx4)0.0f;

  const int rsA = wave * 32 + (lane >> 3);        // A staging row base (+j*8)
  const int rsB = wave * (BNT / 4) + (lane >> 3); // B staging row base (+j*8)
  const int cph = lane & 7;                       // physical chunk this lane fills

#define GSTAGE(k0_, As_, Bs_)                                                  \
  {                                                                            \
    _Pragma("unroll")                                                          \
    for (int j = 0; j < 4; j++) {                                              \
      int r = rsA + j * 8;                                                     \
      int cl = cph ^ (r & 7);                                                  \
      gl_lds16(A + (size_t)(m0 + r) * K + (k0_) + cl * 8,                      \
               (As_) + (wave * 32 + j * 8) * 64);                              \
    }                                                                          \
    _Pragma("unroll")                                                          \
    for (int j = 0; j < BNT / 32; j++) {                                       \
      int r = rsB + j * 8;                                                     \
      int cl = cph ^ (r & 7);                                                  \
      gl_lds16(Bt + (size_t)(n0 + r) * K + (k0_) + cl * 8,                     \
               (Bs_) + (wave * (BNT / 4) + j * 8) * 64);                       \
    }                                                                          \
  }

  // prologue: stage k-tile 0 into buffer 0 (__syncthreads drains vmcnt(0))
  GSTAGE(0, AsB, BsB);
  __syncthreads();

  int cur = 0;
  for (int k0 = 0; k0 < K; k0 += 64) {
    if (k0 + 64 < K)
      GSTAGE(k0 + 64, AsB + (cur ^ 1) * (128 * 64), BsB + (cur ^ 1) * (BNT * 64));
    const unsigned short* As = AsB + cur * (128 * 64);
    const unsigned short* Bs = BsB + cur * (BNT * 64);

#pragma unroll
    for (int ks = 0; ks < 2; ks++) {
      short8 af[4], bf[NI];
#pragma unroll
      for (int mi = 0; mi < 4; mi++) {
        int r = wm + mi * 16 + lane15;
        int phys = (ks * 4 + quad) ^ (r & 7);
        af[mi] = *(const short8*)(&As[r * 64 + phys * 8]);
      }
#pragma unroll
      for (int ni = 0; ni < NI; ni++) {
        int r = wn + ni * 16 + lane15;
        int phys = (ks * 4 + quad) ^ (r & 7);
        bf[ni] = *(const short8*)(&Bs[r * 64 + phys * 8]);
      }
#pragma unroll
      for (int mi = 0; mi < 4; mi++)
#pragma unroll
        for (int ni = 0; ni < NI; ni++)
          acc[mi][ni] = __builtin_amdgcn_mfma_f32_16x16x32_bf16(af[mi], bf[ni],
                                                                acc[mi][ni], 0, 0, 0);
    }
    __syncthreads();   // drains vmcnt(0): next tile staged; cur reads done
    cur ^= 1;
  }
#undef GSTAGE

#pragma unroll
  for (int mi = 0; mi < 4; mi++)
#pragma unroll
    for (int ni = 0; ni < NI; ni++)
#pragma unroll
      for (int reg = 0; reg < 4; reg++) {
        int row = m0 + wm + mi * 16 + quad * 4 + reg;
        int col = n0 + wn + ni * 16 + lane15;
        float v = acc[mi][ni][reg];
        if (BF16OUT)
          ((unsigned short*)C)[(size_t)row * N + col] = f2bf(v);
        else
          ((float*)C)[(size_t)row * N + col] = v;
      }
}

template <bool BF16OUT, int BNT>
__global__ __launch_bounds__(256, BNT == 64 ? 2 : 1) void gemm_bt(
    const unsigned short* __restrict__ A, const unsigned short* __restrict__ Bt,
    void* __restrict__ C, int M, int N, int K) {
  __shared__ __align__(16) unsigned short As[2 * 128 * 64];
  __shared__ __align__(16) unsigned short Bs[2 * BNT * 64];
  gemm_body<BF16OUT, BNT>(As, Bs, A, Bt, C, M, N, K, blockIdx.x, blockIdx.y);
}

__global__ __launch_bounds__(256) void qkv_gemm(const unsigned short* __restrict__ xB,
                                                const unsigned short* __restrict__ WT,
                                                unsigned short* __restrict__ qkB,
                                                unsigned short* __restrict__ vTB) {
  __shared__ __align__(16) unsigned short As[2 * 128 * 64];
  __shared__ __align__(16) unsigned short Bs[2 * 128 * 64];
  const int id = blockIdx.x;
  if (id < 512) {
    gemm_body<true, 128>(As, Bs, xB, WT, qkB, 4096, 2048, 1024, id & 15, id >> 4);
  } else {
    const int t = id - 512;
    gemm_body<true, 64>(As, Bs, WT + (size_t)2048 * 1024, xB, vTB, 1024, 4096, 1024,
                        t & 63, t >> 6);
  }
}

// ---------------------------------------------------------------------------
// MFMA flash differential attention, 32x32x16 swapped-QK^T, SPLIT-S waves.
// [Structure byte-identical to R15-verified.] R17: permlane asms RESTORED to
// volatile (R16 lesson: cross-lane asm depends on partner-lane timing -- the
// compiler may rematerialize/move non-volatile asm, corrupting the swap;
// "+v" only expresses per-lane dataflow). KEPT from R16: lsum 4-way tree
// partials (pure fp add reorder -> ulp-level drift only, breaks the 32-deep
// serial add chain).
// NOTE: split-kb retired (R3,R11); setprio null (R13); GEMM frozen.
// ---------------------------------------------------------------------------
__global__ __launch_bounds__(512) void flash_attn_mfma(
    const unsigned short* __restrict__ qkB, const unsigned short* __restrict__ vTB,
    const float* __restrict__ lq1, const float* __restrict__ lq2,
    const float* __restrict__ lk1, const float* __restrict__ lk2,
    const float* __restrict__ norm_w, unsigned short* __restrict__ hid) {
  __shared__ __align__(16) unsigned short KV[2][2][64 * 64];   // [buf][0=K,1=V]
  __shared__ float Lex[4][64];                                 // sw=1 lsum
  __shared__ unsigned short LF2[64][130];                      // [d][q] bf16 out

  const int tid = threadIdx.x;
  const int wave = tid >> 6, lane = tid & 63;
  const int l31 = lane & 31, hi = lane >> 5;
  const int qsub = wave >> 1, sw = wave & 1;

  // bijective XCD swizzle: the 16 q-tiles sharing one (b,h)'s K/V land on one XCD
  const int bid = (blockIdx.x & 7) * 64 + (blockIdx.x >> 3);   // 512 blocks
  const int qt = bid & 15;
  const int h = (bid >> 4) & 15;
  const int b = bid >> 8;
  const int q0 = qt * 128;

  float a1 = 0.f, a2 = 0.f;
  for (int d = 0; d < HD_; d++) {
    a1 += lq1[d] * lk1[d];
    a2 += lq2[d] * lk2[d];
  }
  const float lam = __expf(a1) - __expf(a2) + LAMBDA_INIT;

  // Q fragments for MY branch: Q[q = q0+qsub*32+l31][h*64 + sw*32 + cs*16 + hi*8]
  short8 qf[2];
  {
    const unsigned short* qrow =
        qkB + (size_t)(b * S_ + q0 + qsub * 32 + l31) * 2048 + h * 64 + sw * 32;
#pragma unroll
    for (int cs = 0; cs < 2; cs++)
      qf[cs] = *(const short8*)(qrow + cs * 16 + hi * 8);
  }

  floatx16 accO[2];
#pragma unroll
  for (int n = 0; n < 2; n++) accO[n] = (floatx16)0.0f;
  float lsum = 0.f;
  const floatx16 zero16 = (floatx16)0.0f;

  const int srow = tid >> 3;   // 512 threads cover all 64 rows in one round
  const int scol = tid & 7;    // physical 16B chunk this lane fills
  const size_t kgbase = (size_t)(b * S_) * 2048 + 1024 + h * 64;
  const size_t vgbase = (size_t)h * 64 * 4096 + b * 2048;

  // stage tile t into buffer buf: 1 K + 1 V gl_lds per thread
#define STAGE(t_, buf_)                                                        \
  {                                                                            \
    const size_t kg_ = kgbase + (size_t)(t_) * 64 * 2048;                      \
    const size_t vg_ = vgbase + (size_t)(t_) * 64;                             \
    const int cl_ = scol ^ (srow & 7);                                         \
    gl_lds16(qkB + kg_ + (size_t)srow * 2048 + cl_ * 8,                        \
             &KV[buf_][0][(wave * 8) * 64]);                                   \
    gl_lds16(vTB + vg_ + (size_t)srow * 4096 + cl_ * 8,                        \
             &KV[buf_][1][(wave * 8) * 64]);                                   \
  }

  // prologue: stage tile 0 into buffer 0
  STAGE(0, 0);
  __syncthreads();

  int cur = 0;
  for (int t = 0; t < S_ / 64; t++) {
    if (t < S_ / 64 - 1) STAGE(t + 1, cur ^ 1);   // async prefetch
    const unsigned short* Kc = &KV[cur][0][0];
    const unsigned short* Vc = &KV[cur][1][0];

#pragma unroll
    for (int kb = 0; kb < 2; kb++) {
      const int krow = kb * 32 + l31;
      const int kx = krow & 7;
      floatx16 accS = zero16;
#pragma unroll
      for (int cs = 0; cs < 2; cs++) {
        const int pc = (sw * 4 + cs * 2 + hi) ^ kx;
        const short8 kf = *(const short8*)(Kc + krow * 64 + pc * 8);
        accS = __builtin_amdgcn_mfma_f32_32x32x16_bf16(kf, qf[cs], accS, 0, 0, 0);
      }
      // accS: q = l31 (col), k row = (reg&3) + 8*(reg>>2) + 4*hi
      unsigned w[8];
      float lsp[4] = {0.f, 0.f, 0.f, 0.f};   // 4-way tree partials (ILP)
#pragma unroll
      for (int i = 0; i < 8; i++) {
        float p0 = __builtin_amdgcn_exp2f(accS[2 * i] * 0.18033688f);
        float p1 = __builtin_amdgcn_exp2f(accS[2 * i + 1] * 0.18033688f);
        lsp[i & 3] += p0 + p1;
        asm("v_cvt_pk_bf16_f32 %0, %1, %2" : "=v"(w[i]) : "v"(p0), "v"(p1));
      }
      lsum += (lsp[0] + lsp[1]) + (lsp[2] + lsp[3]);
      // dst.hi <-> src.lo: dst = low k-quad pack, src = high k-quad pack
      // volatile REQUIRED: cross-lane op, execution point must be pinned (R16)
      asm volatile("v_permlane32_swap_b32 %0, %1" : "+v"(w[0]), "+v"(w[2]));
      asm volatile("v_permlane32_swap_b32 %0, %1" : "+v"(w[1]), "+v"(w[3]));
      asm volatile("v_permlane32_swap_b32 %0, %1" : "+v"(w[4]), "+v"(w[6]));
      asm volatile("v_permlane32_swap_b32 %0, %1" : "+v"(w[5]), "+v"(w[7]));
      uint4 u0 = make_uint4(w[0], w[1], w[2], w[3]);
      uint4 u1 = make_uint4(w[4], w[5], w[6], w[7]);
      short8 pf0 = __builtin_bit_cast(short8, u0);
      short8 pf1 = __builtin_bit_cast(short8, u1);
      // PV for MY branch over this kb
#pragma unroll
      for (int ks2 = 0; ks2 < 2; ks2++) {
        const short8 pa = ks2 ? pf1 : pf0;
#pragma unroll
        for (int n = 0; n < 2; n++) {
          const int vrow = n * 32 + l31;
          const int pc = (kb * 4 + ks2 * 2 + hi) ^ (vrow & 7);
          const short8 vf = *(const short8*)(Vc + vrow * 64 + pc * 8);
          accO[n] = __builtin_amdgcn_mfma_f32_32x32x16_bf16(pa, vf, accO[n], 0, 0, 0);
        }
      }
    }
    __syncthreads();   // drains vmcnt(0): next tile staged; cur free to overwrite
    cur ^= 1;
  }
#undef STAGE

  // finalize row sums (partner lane-half holds complementary k rows)
  lsum += __shfl_xor(lsum, 32, 64);

  // ---- index-matched exchange: sw=1 pushes partials, sw=0 combines ----
  float* LF = (float*)&KV[0][0][0];   // 8192 floats = the dead K/V buffers
  if (sw == 1) {
    Lex[qsub][lane] = lsum;
#pragma unroll
    for (int n = 0; n < 2; n++)
#pragma unroll
      for (int r = 0; r < 16; r++)
        LF[qsub * 2048 + (n * 16 + r) * 64 + lane] = accO[n][r];
  }
  __syncthreads();

  if (sw == 0) {
    const float ls2v = Lex[qsub][lane];
    const float* nw = norm_w + h * HD_;
    const float nw0 = nw[l31], nw1 = nw[32 + l31];
#pragma unroll
    for (int r = 0; r < 16; r++) {
      const int qr = (r & 3) + 8 * (r >> 2) + 4 * hi;   // q row within wave's 32
      const float s1 = __shfl(lsum, qr, 64);
      const float s2 = __shfl(ls2v, qr, 64);
      const float inv1 = 1.0f / s1;
      const float c2 = lam / s2;
      const float b0 = LF[qsub * 2048 + (0 * 16 + r) * 64 + lane];
      const float b1 = LF[qsub * 2048 + (1 * 16 + r) * 64 + lane];
      float o0 = accO[0][r] * inv1 - b0 * c2;   // d = l31
      float o1 = accO[1][r] * inv1 - b1 * c2;   // d = 32 + l31
      float ss = o0 * o0 + o1 * o1;
#pragma unroll
      for (int msk = 1; msk <= 16; msk <<= 1) ss += __shfl_xor(ss, msk, 64);
      const float rsc = (1.0f - LAMBDA_INIT) * rsqrtf(ss * (1.0f / 64.0f) + EPS_);
      // bf16 conversion here (same values, same f2bf) -> bitwise-same out
      LF2[l31][qsub * 32 + qr] = f2bf(o0 * rsc * nw0);
      LF2[32 + l31][qsub * 32 + qr] = f2bf(o1 * rsc * nw1);
    }
  }
  __syncthreads();

  // ---- fused reshape: all 512 threads, d-major coalesced bf16 store ----
  // hidden[b*S*E + d*H*S + h*S + (q0 + qq)] = LF2[d][qq] (already bf16)
  {
    const int d = tid >> 3, g = tid & 7;
    unsigned short* dst =
        hid + (size_t)b * (S_ * E_) + (size_t)d * (H_ * S_) + h * S_ + q0 + g * 16;
    ushort8v v0, v1;
#pragma unroll
    for (int j = 0; j < 8; j++) {
      v0[j] = LF2[d][g * 16 + j];
      v1[j] = LF2[d][g * 16 + 8 + j];
    }
    *(ushort8v*)(dst) = v0;
    *(ushort8v*)(dst + 8) = v1;
  }
}

// ---------------------------------------------------------------------------
extern "C" void kernel_launch(void* const* d_in, const int* in_sizes, int n_in,
                              void* d_out, int out_size, void* d_ws, size_t ws_size,
                              hipStream_t stream) {
  const float* x = (const float*)d_in[0];
  const float* w_qkv = (const float*)d_in[1];
  const float* wo = (const float*)d_in[2];
  const float* lq1 = (const float*)d_in[3];
  const float* lq2 = (const float*)d_in[4];
  const float* lk1 = (const float*)d_in[5];
  const float* lk2 = (const float*)d_in[6];
  const float* norm_w = (const float*)d_in[7];
  float* out = (float*)d_out;

  unsigned short* xB = (unsigned short*)d_ws;             // 4096*1024
  unsigned short* WT = xB + (size_t)4096 * 1024;          // 3072*1024 (w_qkv^T)
  unsigned short* woT = WT + (size_t)3072 * 1024;         // 1024*1024
  unsigned short* qkB = woT + (size_t)1024 * 1024;        // 4096*2048
  unsigned short* vTB = qkB + (size_t)4096 * 2048;        // 1024*4096
  unsigned short* hidB = vTB + (size_t)1024 * 4096;       // 4096*1024

  // 0) fused bf16 cast + transposes of inputs (one launch)
  prep<<<2048, 256, 0, stream>>>(x, w_qkv, wo, xB, WT, woT);

  // 1) MERGED: {q,k = x @ Wqk -> qkB} + {vT = Wv^T @ x^T -> vTB} (1024 blocks)
  qkv_gemm<<<1024, 256, 0, stream>>>(xB, WT, qkB, vTB);

  // 2) MFMA differential flash attention + RMSNorm + fused reshape -> hidB bf16
  flash_attn_mfma<<<B_ * H_ * (S_ / 128), 512, 0, stream>>>(qkB, vTB, lq1, lq2, lk1,
                                                            lk2, norm_w, hidB);
  // 3) out = hidden @ wo (fp32 out)  (128x64 tile: 512 blocks, 2 blocks/CU)
  gemm_bt<false, 64><<<dim3(1024 / 64, 4096 / 128), 256, 0, stream>>>(
      hidB, woT, (void*)out, 4096, 1024, 1024);
}